// Round 15
// baseline (425.511 us; speedup 1.0000x reference)
//
#include <hip/hip_runtime.h>
#include <stdint.h>

typedef __attribute__((ext_vector_type(8))) short short8;
typedef __attribute__((ext_vector_type(4))) float f32x4;
typedef __attribute__((ext_vector_type(4))) unsigned short us4;

#define DI __device__ __forceinline__

static constexpr int Dm = 1024;   // hidden dim
static constexpr int Sm = 4096;   // latent tokens
static constexpr int Em = 160;    // encoder tokens
static constexpr int Hm = 16;     // heads

// workspace layout (bytes)
static constexpr size_t OFF_HSB  = 0;           // hs bf16 [8*4096][1024] (stays live: O-proj resid)
static constexpr size_t OFF_WT   = 67108864;    // 4x Wt bf16 [1024][1024] (transposed: [N][K])
static constexpr size_t OFF_QB   = 75497472;    // Q bf16 [8*4096][1024]; attn overwrites IN-PLACE
static constexpr size_t OFF_KB   = 142606336;   // K bf16 [8*160][1024]
static constexpr size_t OFF_KBAR = 145227776;   // k-bar bf16 [8][16][64] (mean K row per bc,h)
static constexpr size_t OFF_VT   = 147849216;   // V^T bf16 [8][16][64][192]
static constexpr size_t OFF_EHSB = 150994944;   // ehs bf16 [8*160][1024]

DI unsigned short f2b(float f) {
  union { float f; unsigned u; } x; x.f = f;
  unsigned r = x.u + 0x7fffu + ((x.u >> 16) & 1u);
  return (unsigned short)(r >> 16);
}

DI float b2f(unsigned short h) {
  union { unsigned u; float f; } x; x.u = ((unsigned)h) << 16; return x.f;
}

DI void gl_lds16(const void* g, void* l) {
  __builtin_amdgcn_global_load_lds(
      (const __attribute__((address_space(1))) unsigned int*)g,
      (__attribute__((address_space(3))) unsigned int*)l, 16, 0, 0);
}

// ---------------- prep: W transpose+cvt || ehs cvt || hs cvt (one launch) ----------------
__global__ void k_prep(const float* __restrict__ ehs, unsigned short* __restrict__ eb,
                       const float* __restrict__ hs, unsigned short* __restrict__ hsb,
                       const float* __restrict__ W0, const float* __restrict__ W1,
                       const float* __restrict__ W2, const float* __restrict__ W3,
                       unsigned short* __restrict__ Wt) {
  __shared__ float t[32][33];
  const int bid = blockIdx.x, tid = threadIdx.x;
  if (bid < 4096) {
    const int bz = bid >> 10, rest = bid & 1023, by = rest >> 5, bx = rest & 31;
    const float* W = (bz == 0) ? W0 : (bz == 1) ? W1 : (bz == 2) ? W2 : W3;
    unsigned short* o = Wt + (size_t)bz * 1048576;
    const int tx = tid & 31, ty = tid >> 5;
    const int n = bx * 32 + tx, k0 = by * 32;
    #pragma unroll
    for (int j = ty; j < 32; j += 8) t[j][tx] = W[(size_t)(k0 + j) * 1024 + n];
    __syncthreads();
    #pragma unroll
    for (int j = ty; j < 32; j += 8)
      o[(size_t)(bx * 32 + j) * 1024 + k0 + tx] = f2b(t[tx][j]);
  } else if (bid < 5376) {
    const int i = (bid - 4096) * 256 + tid;
    float4 v = ((const float4*)ehs)[i];
    us4 o = { f2b(v.x), f2b(v.y), f2b(v.z), f2b(v.w) };
    *(us4*)(eb + (size_t)i * 4) = o;
  } else {
    for (int i = (bid - 5376) * 256 + tid; i < 8388608; i += 2048 * 256) {
      float4 v = ((const float4*)hs)[i];
      us4 o = { f2b(v.x), f2b(v.y), f2b(v.z), f2b(v.w) };
      *(us4*)(hsb + (size_t)i * 4) = o;
    }
  }
}

// ---------------- fused Q + K + V projection GEMM (one launch) ----------------
__global__ __launch_bounds__(256, 4) void k_gemm_qkv(const unsigned short* __restrict__ hsb,
                                                     const unsigned short* __restrict__ eb,
                                                     const unsigned short* __restrict__ Wt,
                                                     unsigned short* __restrict__ qb,
                                                     unsigned short* __restrict__ kb,
                                                     unsigned short* __restrict__ vt) {
  __shared__ __align__(16) char smem[32768];
  char* As = smem;
  char* Bs = smem + 16384;
  const int bid = blockIdx.x, tid = threadIdx.x;
  const int lane = tid & 63;
  const int l15 = lane & 15;
  const int g = lane >> 4;
  const int wv = tid >> 6;
  const int wr = wv >> 1, wc = wv & 1;

  const bool isKV = (bid < 160);
  int m0, n0;
  const unsigned short *Ap, *Bt;
  if (isKV) {
    const int z = bid / 80, rr = bid - z * 80;
    m0 = (rr % 10) * 128; n0 = (rr / 10) * 128;
    Ap = eb; Bt = Wt + (size_t)(1 + z) * 1048576;
  } else {
    const int q = bid - 160;
    m0 = ((q >> 6) * 8 + (q & 7)) * 128;
    n0 = ((q >> 3) & 7) * 128;
    Ap = hsb; Bt = Wt;
  }

  f32x4 acc[4][4];
  #pragma unroll
  for (int i = 0; i < 4; ++i)
    #pragma unroll
    for (int j = 0; j < 4; ++j) acc[i][j] = (f32x4){0.f, 0.f, 0.f, 0.f};

  for (int t = 0; t < 16; ++t) {
    __syncthreads();
    #pragma unroll
    for (int is = 0; is < 4; ++is) {
      int ch = is * 256 + tid;
      int row = ch >> 3, j = ch & 7;
      int sj = (j ^ (row & 7)) * 8;
      gl_lds16(Ap + (size_t)(m0 + row) * 1024 + t * 64 + sj, As + ch * 16);
      gl_lds16(Bt + (size_t)(n0 + row) * 1024 + t * 64 + sj, Bs + ch * 16);
    }
    __syncthreads();
    short8 af[2][4], bf[2][4];
    #pragma unroll
    for (int kk = 0; kk < 2; ++kk)
      #pragma unroll
      for (int mt = 0; mt < 4; ++mt) {
        af[kk][mt] = *(const short8*)(As + (wr * 64 + mt * 16 + l15) * 128 + ((kk * 64 + g * 16) ^ ((l15 & 7) << 4)));
        bf[kk][mt] = *(const short8*)(Bs + (wc * 64 + mt * 16 + l15) * 128 + ((kk * 64 + g * 16) ^ ((l15 & 7) << 4)));
      }
    #pragma unroll
    for (int kk = 0; kk < 2; ++kk)
      #pragma unroll
      for (int mt = 0; mt < 4; ++mt)
        #pragma unroll
        for (int nt = 0; nt < 4; ++nt)
          acc[mt][nt] = __builtin_amdgcn_mfma_f32_16x16x32_bf16(af[kk][mt], bf[kk][nt], acc[mt][nt], 0, 0, 0);
  }

  if (isKV) {
    const int z = bid / 80;
    #pragma unroll
    for (int mt = 0; mt < 4; ++mt)
      #pragma unroll
      for (int nt = 0; nt < 4; ++nt)
        #pragma unroll
        for (int r = 0; r < 4; ++r) {
          int row = m0 + wr * 64 + mt * 16 + 4 * g + r;   // [0,1280)
          int col = n0 + wc * 64 + nt * 16 + l15;         // [0,1024)
          unsigned short hv = f2b(acc[mt][nt][r]);
          if (z == 0) {
            kb[(size_t)row * 1024 + col] = hv;
          } else {
            int bc = row / 160, e = row - bc * 160;       // h = col>>6, d = col&63
            vt[((size_t)(bc * 16 + (col >> 6)) * 64 + (col & 63)) * 192 + e] = hv;
          }
        }
  } else {
    __syncthreads();
    unsigned short* Cl = (unsigned short*)smem;
    #pragma unroll
    for (int mt = 0; mt < 4; ++mt)
      #pragma unroll
      for (int nt = 0; nt < 4; ++nt)
        #pragma unroll
        for (int r = 0; r < 4; ++r)
          Cl[(wr * 64 + mt * 16 + 4 * g + r) * 128 + wc * 64 + nt * 16 + l15] = f2b(acc[mt][nt][r]);
    __syncthreads();
    #pragma unroll
    for (int j = 0; j < 8; ++j) {
      int ch = j * 256 + tid;
      int row = ch >> 4, sl = ch & 15;
      __builtin_nontemporal_store(*(const short8*)(Cl + row * 128 + sl * 8),
          (short8*)(qb + (size_t)(m0 + row) * 1024 + n0 + sl * 8));
    }
  }
}

// ---------------- k-bar: mean K row per (bc,h) ----------------
__global__ void k_kbar(const unsigned short* __restrict__ kb, unsigned short* __restrict__ kbar) {
  const int bh = blockIdx.x, d = threadIdx.x;
  const int bc = bh >> 4, h = bh & 15;
  const unsigned short* src = kb + ((size_t)bc * Em) * Dm + h * 64 + d;
  float s = 0.f;
  #pragma unroll 4
  for (int e = 0; e < Em; ++e) s += b2f(src[(size_t)e * Dm]);
  kbar[(size_t)bh * 64 + d] = f2b(s * (1.f / 160.f));
}

// ---------------- O-projection GEMM: fp32 out + bias + bf16 residual ----------------
__global__ __launch_bounds__(256, 4) void k_gemm_o(const unsigned short* __restrict__ A,
                                                   const unsigned short* __restrict__ Bt,
                                                   float* __restrict__ Cout,
                                                   const float* __restrict__ bias,
                                                   const unsigned short* __restrict__ residb) {
  __shared__ __align__(16) char smem[32768];
  char* As = smem;
  char* Bs = smem + 16384;
  const int tid = threadIdx.x;
  const int lane = tid & 63;
  const int l15 = lane & 15;
  const int g = lane >> 4;
  const int wv = tid >> 6;
  const int wr = wv >> 1, wc = wv & 1;
  const int bid = blockIdx.x;
  const int m0 = ((bid >> 6) * 8 + (bid & 7)) * 128;
  const int n0 = ((bid >> 3) & 7) * 128;

  f32x4 acc[4][4];
  #pragma unroll
  for (int i = 0; i < 4; ++i)
    #pragma unroll
    for (int j = 0; j < 4; ++j) acc[i][j] = (f32x4){0.f, 0.f, 0.f, 0.f};

  for (int t = 0; t < 16; ++t) {
    __syncthreads();
    #pragma unroll
    for (int is = 0; is < 4; ++is) {
      int ch = is * 256 + tid;
      int row = ch >> 3, j = ch & 7;
      int sj = (j ^ (row & 7)) * 8;
      gl_lds16(A  + (size_t)(m0 + row) * 1024 + t * 64 + sj, As + ch * 16);
      gl_lds16(Bt + (size_t)(n0 + row) * 1024 + t * 64 + sj, Bs + ch * 16);
    }
    __syncthreads();
    short8 af[2][4], bf[2][4];
    #pragma unroll
    for (int kk = 0; kk < 2; ++kk)
      #pragma unroll
      for (int mt = 0; mt < 4; ++mt) {
        af[kk][mt] = *(const short8*)(As + (wr * 64 + mt * 16 + l15) * 128 + ((kk * 64 + g * 16) ^ ((l15 & 7) << 4)));
        bf[kk][mt] = *(const short8*)(Bs + (wc * 64 + mt * 16 + l15) * 128 + ((kk * 64 + g * 16) ^ ((l15 & 7) << 4)));
      }
    #pragma unroll
    for (int kk = 0; kk < 2; ++kk)
      #pragma unroll
      for (int mt = 0; mt < 4; ++mt)
        #pragma unroll
        for (int nt = 0; nt < 4; ++nt)
          acc[mt][nt] = __builtin_amdgcn_mfma_f32_16x16x32_bf16(af[kk][mt], bf[kk][nt], acc[mt][nt], 0, 0, 0);
  }

  #pragma unroll
  for (int mt = 0; mt < 4; ++mt)
    #pragma unroll
    for (int nt = 0; nt < 4; ++nt)
      #pragma unroll
      for (int r = 0; r < 4; ++r) {
        size_t row = (size_t)(m0 + wr * 64 + mt * 16 + 4 * g + r);
        int col = n0 + wc * 64 + nt * 16 + l15;
        size_t idx = row * 1024 + col;
        unsigned short rh = __builtin_nontemporal_load(residb + idx);
        Cout[idx] = acc[mt][nt][r] + bias[col] + b2f(rh);
      }
}

// ---------------- fused decomposing attention v5 (barrier-free strips) ----------------
// v4 + restructure: all 4 strips run back-to-back with NO per-strip barrier
// (per-wave P buffer reuse is ordered by program order within the wave; pooled[]
// is strip-indexed), PV accumulators oa4[st] and rs44[st] stay live; then ONE
// __syncthreads(); then all 4 epilogues. Removes 3 s_barrier scheduling fences ->
// compiler can overlap strip i+1's K-loads/QK^T MFMAs with strip i's softmax VALU
// (separate pipes, m114). Peak regs ~165 <= 256 at (256,2) — no spill expected.
// __launch_bounds__(256,2): MUST stay 2 (R2/R13: higher caps VGPR -> scratch).
__global__ __launch_bounds__(256, 2) void k_attn(unsigned short* __restrict__ Qb,
                                                 const unsigned short* __restrict__ Kb,
                                                 const unsigned short* __restrict__ Vt,
                                                 const unsigned short* __restrict__ Kbar) {
  __shared__ __align__(16) char smem[22528];
  float* pooled = (float*)(smem + 21504);   // [4 strips][16 rows][4 comps] f32
  const int tid = threadIdx.x, lane = tid & 63, wv = tid >> 6;
  const int g = lane >> 4, l15 = lane & 15;
  const int s0 = blockIdx.x * 64;
  const int h = blockIdx.y;
  const int b = blockIdx.z;
  const int bc = wv * 2 + b;
  const float scale = 0.125f;

  unsigned short* Qp = Qb + ((size_t)bc * Sm + s0) * Dm + h * 64;
  const unsigned short* Kp = Kb + (size_t)bc * Em * Dm + h * 64;
  const unsigned short* Vp = Vt + ((size_t)bc * Hm + h) * (64 * 192);
  char* Pw = smem + wv * 5376;              // [16 rows][336B] per wave, reused per strip

  const unsigned short* kbp = Kbar + (size_t)(bc * 16 + h) * 64;
  short8 kbf[2];
  #pragma unroll
  for (int kk = 0; kk < 2; ++kk)
    kbf[kk] = *(const short8*)(kbp + kk * 32 + g * 8);

  f32x4 oa4[4][4];
  float rs44[4][4];

  #pragma unroll
  for (int st = 0; st < 4; ++st) {
    // ---- QK^T + pooled (q.kbar) ----
    short8 qf[2];
    #pragma unroll
    for (int kk = 0; kk < 2; ++kk)
      qf[kk] = *(const short8*)(Qp + (size_t)(st * 16 + l15) * Dm + kk * 32 + g * 8);
    f32x4 scb = (f32x4){0.f, 0.f, 0.f, 0.f};
    #pragma unroll
    for (int kk = 0; kk < 2; ++kk)
      scb = __builtin_amdgcn_mfma_f32_16x16x32_bf16(qf[kk], kbf[kk], scb, 0, 0, 0);
    f32x4 sc[10];
    #pragma unroll
    for (int et = 0; et < 10; ++et) {
      sc[et] = (f32x4){0.f, 0.f, 0.f, 0.f};
      #pragma unroll
      for (int kk = 0; kk < 2; ++kk) {
        short8 kf = *(const short8*)(Kp + (size_t)(et * 16 + l15) * Dm + kk * 32 + g * 8);
        sc[et] = __builtin_amdgcn_mfma_f32_16x16x32_bf16(qf[kk], kf, sc[et], 0, 0, 0);
      }
    }
    // ---- softmax numerators (no max-subtract) + rs reduce; publish pooled ----
    #pragma unroll
    for (int r = 0; r < 4; ++r) {
      if (l15 == 0) pooled[(st * 16 + 4 * g + r) * 4 + wv] = scb[r] * scale;
      float rs = 0.f;
      #pragma unroll
      for (int et = 0; et < 10; ++et) {
        float p = __expf(sc[et][r] * scale);
        rs += p;
        *(unsigned short*)(Pw + (4 * g + r) * 336 + (et * 16 + l15) * 2) = f2b(p);
      }
      rs += __shfl_xor(rs, 1); rs += __shfl_xor(rs, 2); rs += __shfl_xor(rs, 4); rs += __shfl_xor(rs, 8);
      rs44[st][r] = rs;
    }
    // ---- PV (P from per-wave LDS transpose, V^T direct from global) ----
    #pragma unroll
    for (int dt = 0; dt < 4; ++dt) oa4[st][dt] = (f32x4){0.f, 0.f, 0.f, 0.f};
    #pragma unroll
    for (int k5 = 0; k5 < 5; ++k5) {
      short8 pf = *(const short8*)(Pw + l15 * 336 + k5 * 64 + g * 16);
      #pragma unroll
      for (int dt = 0; dt < 4; ++dt) {
        short8 vf = *(const short8*)(Vp + (size_t)(dt * 16 + l15) * 192 + k5 * 32 + g * 8);
        oa4[st][dt] = __builtin_amdgcn_mfma_f32_16x16x32_bf16(pf, vf, oa4[st][dt], 0, 0, 0);
      }
    }
  }

  __syncthreads();   // single barrier: all waves' pooled[*] visible

  #pragma unroll
  for (int st = 0; st < 4; ++st)
    #pragma unroll
    for (int r = 0; r < 4; ++r) {
      float4 pl = *(const float4*)&pooled[(st * 16 + 4 * g + r) * 4];
      float m3 = fmaxf(fmaxf(pl.x, pl.y), fmaxf(pl.z, pl.w));
      float ssum = __expf(pl.x - m3) + __expf(pl.y - m3) + __expf(pl.z - m3) + __expf(pl.w - m3);
      float mine = (wv == 0) ? pl.x : (wv == 1) ? pl.y : (wv == 2) ? pl.z : pl.w;
      float srw = __expf(mine - m3) / (ssum * rs44[st][r]);
      #pragma unroll
      for (int dt = 0; dt < 4; ++dt)
        Qp[(size_t)(st * 16 + 4 * g + r) * Dm + dt * 16 + l15] = f2b(oa4[st][dt][r] * srw);
    }
}

extern "C" void kernel_launch(void* const* d_in, const int* in_sizes, int n_in,
                              void* d_out, int out_size, void* d_ws, size_t ws_size,
                              hipStream_t stream) {
  const float* hs  = (const float*)d_in[0];
  const float* ehs = (const float*)d_in[1];
  const float* Wq  = (const float*)d_in[2];
  const float* Wk  = (const float*)d_in[3];
  const float* Wv  = (const float*)d_in[4];
  const float* Wo  = (const float*)d_in[5];
  const float* bo  = (const float*)d_in[6];
  char* ws = (char*)d_ws;
  unsigned short* hsb  = (unsigned short*)(ws + OFF_HSB);
  unsigned short* wt   = (unsigned short*)(ws + OFF_WT);
  unsigned short* qb   = (unsigned short*)(ws + OFF_QB);
  unsigned short* kb   = (unsigned short*)(ws + OFF_KB);
  unsigned short* kbar = (unsigned short*)(ws + OFF_KBAR);
  unsigned short* vt   = (unsigned short*)(ws + OFF_VT);
  unsigned short* eb   = (unsigned short*)(ws + OFF_EHSB);

  hipLaunchKernelGGL(k_prep, dim3(7424), dim3(256), 0, stream, ehs, eb, hs, hsb, Wq, Wk, Wv, Wo, wt);
  hipLaunchKernelGGL(k_gemm_qkv, dim3(2208), dim3(256), 0, stream, hsb, eb, wt, qb, kb, vt);
  hipLaunchKernelGGL(k_kbar, dim3(128), dim3(64), 0, stream, kb, kbar);
  hipLaunchKernelGGL(k_attn, dim3(64, 16, 2), dim3(256), 0, stream, qb, kb, vt, kbar);
  hipLaunchKernelGGL(k_gemm_o, dim3(2048), dim3(256), 0, stream, qb, wt + 3 * 1048576, (float*)d_out, bo, hsb);
}

// Round 16
// 341.364 us; speedup vs baseline: 1.2465x; 1.2465x over previous
//
#include <hip/hip_runtime.h>
#include <hip/hip_bf16.h>
#include <stdint.h>

typedef __attribute__((ext_vector_type(8))) short short8;
typedef __attribute__((ext_vector_type(4))) float f32x4;
typedef __attribute__((ext_vector_type(4))) unsigned short us4;

#define DI __device__ __forceinline__

static constexpr int Dm = 1024;   // hidden dim
static constexpr int Sm = 4096;   // latent tokens
static constexpr int Em = 160;    // encoder tokens
static constexpr int Hm = 16;     // heads

// workspace layout (bytes)
static constexpr size_t OFF_HSB  = 0;           // hs bf16 [8*4096][1024] (stays live: O-proj resid)
static constexpr size_t OFF_WT   = 67108864;    // 4x Wt bf16 [1024][1024] (transposed: [N][K])
static constexpr size_t OFF_QB   = 75497472;    // Q bf16 [8*4096][1024]; attn overwrites IN-PLACE
static constexpr size_t OFF_KB   = 142606336;   // K bf16 [8*160][1024]
static constexpr size_t OFF_KBAR = 145227776;   // k-bar bf16 [8][16][64] (mean K row per bc,h)
static constexpr size_t OFF_VT   = 147849216;   // V^T bf16 [8][16][64][192]
static constexpr size_t OFF_EHSB = 150994944;   // ehs bf16 [8*160][1024]

DI unsigned short f2b(float f) {
  union { float f; unsigned u; } x; x.f = f;
  unsigned r = x.u + 0x7fffu + ((x.u >> 16) & 1u);
  return (unsigned short)(r >> 16);
}

DI float b2f(unsigned short h) {
  union { unsigned u; float f; } x; x.u = ((unsigned)h) << 16; return x.f;
}

DI void gl_lds16(const void* g, void* l) {
  __builtin_amdgcn_global_load_lds(
      (const __attribute__((address_space(1))) unsigned int*)g,
      (__attribute__((address_space(3))) unsigned int*)l, 16, 0, 0);
}

// ---------------- prep: W transpose+cvt || ehs cvt || hs cvt (one launch) ----------------
__global__ void k_prep(const float* __restrict__ ehs, unsigned short* __restrict__ eb,
                       const float* __restrict__ hs, unsigned short* __restrict__ hsb,
                       const float* __restrict__ W0, const float* __restrict__ W1,
                       const float* __restrict__ W2, const float* __restrict__ W3,
                       unsigned short* __restrict__ Wt) {
  __shared__ float t[32][33];
  const int bid = blockIdx.x, tid = threadIdx.x;
  if (bid < 4096) {
    const int bz = bid >> 10, rest = bid & 1023, by = rest >> 5, bx = rest & 31;
    const float* W = (bz == 0) ? W0 : (bz == 1) ? W1 : (bz == 2) ? W2 : W3;
    unsigned short* o = Wt + (size_t)bz * 1048576;
    const int tx = tid & 31, ty = tid >> 5;
    const int n = bx * 32 + tx, k0 = by * 32;
    #pragma unroll
    for (int j = ty; j < 32; j += 8) t[j][tx] = W[(size_t)(k0 + j) * 1024 + n];
    __syncthreads();
    #pragma unroll
    for (int j = ty; j < 32; j += 8)
      o[(size_t)(bx * 32 + j) * 1024 + k0 + tx] = f2b(t[tx][j]);
  } else if (bid < 5376) {
    const int i = (bid - 4096) * 256 + tid;
    float4 v = ((const float4*)ehs)[i];
    us4 o = { f2b(v.x), f2b(v.y), f2b(v.z), f2b(v.w) };
    *(us4*)(eb + (size_t)i * 4) = o;
  } else {
    for (int i = (bid - 5376) * 256 + tid; i < 8388608; i += 2048 * 256) {
      float4 v = ((const float4*)hs)[i];
      us4 o = { f2b(v.x), f2b(v.y), f2b(v.z), f2b(v.w) };
      *(us4*)(hsb + (size_t)i * 4) = o;
    }
  }
}

// ---------------- fused Q + K + V projection GEMM (one launch) ----------------
__global__ __launch_bounds__(256, 4) void k_gemm_qkv(const unsigned short* __restrict__ hsb,
                                                     const unsigned short* __restrict__ eb,
                                                     const unsigned short* __restrict__ Wt,
                                                     unsigned short* __restrict__ qb,
                                                     unsigned short* __restrict__ kb,
                                                     unsigned short* __restrict__ vt) {
  __shared__ __align__(16) char smem[32768];
  char* As = smem;
  char* Bs = smem + 16384;
  const int bid = blockIdx.x, tid = threadIdx.x;
  const int lane = tid & 63;
  const int l15 = lane & 15;
  const int g = lane >> 4;
  const int wv = tid >> 6;
  const int wr = wv >> 1, wc = wv & 1;

  const bool isKV = (bid < 160);
  int m0, n0;
  const unsigned short *Ap, *Bt;
  if (isKV) {
    const int z = bid / 80, rr = bid - z * 80;
    m0 = (rr % 10) * 128; n0 = (rr / 10) * 128;
    Ap = eb; Bt = Wt + (size_t)(1 + z) * 1048576;
  } else {
    const int q = bid - 160;
    m0 = ((q >> 6) * 8 + (q & 7)) * 128;
    n0 = ((q >> 3) & 7) * 128;
    Ap = hsb; Bt = Wt;
  }

  f32x4 acc[4][4];
  #pragma unroll
  for (int i = 0; i < 4; ++i)
    #pragma unroll
    for (int j = 0; j < 4; ++j) acc[i][j] = (f32x4){0.f, 0.f, 0.f, 0.f};

  for (int t = 0; t < 16; ++t) {
    __syncthreads();
    #pragma unroll
    for (int is = 0; is < 4; ++is) {
      int ch = is * 256 + tid;
      int row = ch >> 3, j = ch & 7;
      int sj = (j ^ (row & 7)) * 8;
      gl_lds16(Ap + (size_t)(m0 + row) * 1024 + t * 64 + sj, As + ch * 16);
      gl_lds16(Bt + (size_t)(n0 + row) * 1024 + t * 64 + sj, Bs + ch * 16);
    }
    __syncthreads();
    short8 af[2][4], bf[2][4];
    #pragma unroll
    for (int kk = 0; kk < 2; ++kk)
      #pragma unroll
      for (int mt = 0; mt < 4; ++mt) {
        af[kk][mt] = *(const short8*)(As + (wr * 64 + mt * 16 + l15) * 128 + ((kk * 64 + g * 16) ^ ((l15 & 7) << 4)));
        bf[kk][mt] = *(const short8*)(Bs + (wc * 64 + mt * 16 + l15) * 128 + ((kk * 64 + g * 16) ^ ((l15 & 7) << 4)));
      }
    #pragma unroll
    for (int kk = 0; kk < 2; ++kk)
      #pragma unroll
      for (int mt = 0; mt < 4; ++mt)
        #pragma unroll
        for (int nt = 0; nt < 4; ++nt)
          acc[mt][nt] = __builtin_amdgcn_mfma_f32_16x16x32_bf16(af[kk][mt], bf[kk][nt], acc[mt][nt], 0, 0, 0);
  }

  if (isKV) {
    const int z = bid / 80;
    #pragma unroll
    for (int mt = 0; mt < 4; ++mt)
      #pragma unroll
      for (int nt = 0; nt < 4; ++nt)
        #pragma unroll
        for (int r = 0; r < 4; ++r) {
          int row = m0 + wr * 64 + mt * 16 + 4 * g + r;   // [0,1280)
          int col = n0 + wc * 64 + nt * 16 + l15;         // [0,1024)
          unsigned short hv = f2b(acc[mt][nt][r]);
          if (z == 0) {
            kb[(size_t)row * 1024 + col] = hv;
          } else {
            int bc = row / 160, e = row - bc * 160;       // h = col>>6, d = col&63
            vt[((size_t)(bc * 16 + (col >> 6)) * 64 + (col & 63)) * 192 + e] = hv;
          }
        }
  } else {
    __syncthreads();
    unsigned short* Cl = (unsigned short*)smem;
    #pragma unroll
    for (int mt = 0; mt < 4; ++mt)
      #pragma unroll
      for (int nt = 0; nt < 4; ++nt)
        #pragma unroll
        for (int r = 0; r < 4; ++r)
          Cl[(wr * 64 + mt * 16 + 4 * g + r) * 128 + wc * 64 + nt * 16 + l15] = f2b(acc[mt][nt][r]);
    __syncthreads();
    #pragma unroll
    for (int j = 0; j < 8; ++j) {
      int ch = j * 256 + tid;
      int row = ch >> 4, sl = ch & 15;
      __builtin_nontemporal_store(*(const short8*)(Cl + row * 128 + sl * 8),
          (short8*)(qb + (size_t)(m0 + row) * 1024 + n0 + sl * 8));
    }
  }
}

// ---------------- k-bar: mean K row per (bc,h) ----------------
__global__ void k_kbar(const unsigned short* __restrict__ kb, unsigned short* __restrict__ kbar) {
  const int bh = blockIdx.x, d = threadIdx.x;
  const int bc = bh >> 4, h = bh & 15;
  const unsigned short* src = kb + ((size_t)bc * Em) * Dm + h * 64 + d;
  float s = 0.f;
  #pragma unroll 4
  for (int e = 0; e < Em; ++e) s += b2f(src[(size_t)e * Dm]);
  kbar[(size_t)bh * 64 + d] = f2b(s * (1.f / 160.f));
}

// ---------------- O-projection GEMM: fp32 out + bias + bf16 residual ----------------
__global__ __launch_bounds__(256, 4) void k_gemm_o(const unsigned short* __restrict__ A,
                                                   const unsigned short* __restrict__ Bt,
                                                   float* __restrict__ Cout,
                                                   const float* __restrict__ bias,
                                                   const unsigned short* __restrict__ residb) {
  __shared__ __align__(16) char smem[32768];
  char* As = smem;
  char* Bs = smem + 16384;
  const int tid = threadIdx.x;
  const int lane = tid & 63;
  const int l15 = lane & 15;
  const int g = lane >> 4;
  const int wv = tid >> 6;
  const int wr = wv >> 1, wc = wv & 1;
  const int bid = blockIdx.x;
  const int m0 = ((bid >> 6) * 8 + (bid & 7)) * 128;
  const int n0 = ((bid >> 3) & 7) * 128;

  f32x4 acc[4][4];
  #pragma unroll
  for (int i = 0; i < 4; ++i)
    #pragma unroll
    for (int j = 0; j < 4; ++j) acc[i][j] = (f32x4){0.f, 0.f, 0.f, 0.f};

  for (int t = 0; t < 16; ++t) {
    __syncthreads();
    #pragma unroll
    for (int is = 0; is < 4; ++is) {
      int ch = is * 256 + tid;
      int row = ch >> 3, j = ch & 7;
      int sj = (j ^ (row & 7)) * 8;
      gl_lds16(A  + (size_t)(m0 + row) * 1024 + t * 64 + sj, As + ch * 16);
      gl_lds16(Bt + (size_t)(n0 + row) * 1024 + t * 64 + sj, Bs + ch * 16);
    }
    __syncthreads();
    short8 af[2][4], bf[2][4];
    #pragma unroll
    for (int kk = 0; kk < 2; ++kk)
      #pragma unroll
      for (int mt = 0; mt < 4; ++mt) {
        af[kk][mt] = *(const short8*)(As + (wr * 64 + mt * 16 + l15) * 128 + ((kk * 64 + g * 16) ^ ((l15 & 7) << 4)));
        bf[kk][mt] = *(const short8*)(Bs + (wc * 64 + mt * 16 + l15) * 128 + ((kk * 64 + g * 16) ^ ((l15 & 7) << 4)));
      }
    #pragma unroll
    for (int kk = 0; kk < 2; ++kk)
      #pragma unroll
      for (int mt = 0; mt < 4; ++mt)
        #pragma unroll
        for (int nt = 0; nt < 4; ++nt)
          acc[mt][nt] = __builtin_amdgcn_mfma_f32_16x16x32_bf16(af[kk][mt], bf[kk][nt], acc[mt][nt], 0, 0, 0);
  }

  #pragma unroll
  for (int mt = 0; mt < 4; ++mt)
    #pragma unroll
    for (int nt = 0; nt < 4; ++nt)
      #pragma unroll
      for (int r = 0; r < 4; ++r) {
        size_t row = (size_t)(m0 + wr * 64 + mt * 16 + 4 * g + r);
        int col = n0 + wc * 64 + nt * 16 + l15;
        size_t idx = row * 1024 + col;
        unsigned short rh = __builtin_nontemporal_load(residb + idx);
        Cout[idx] = acc[mt][nt][r] + bias[col] + b2f(rh);
      }
}

// ---------------- fused decomposing attention v6 (v4 body + cvt_pk softmax) ----------------
// Exactly the R12/R14 v4 structure (per-strip barrier — R15's barrier-free variant
// serialized WORSE via Pw-reuse lgkmcnt chains; do not retry). Changes vs v4:
//  - P bf16 conversion via paired __float22bfloat162_rn (v_cvt_pk_bf16_f32):
//    1 op / 2 values instead of ~4 ops/value of manual f2b.
//  - exp via exp2f with pre-folded scale*log2(e) constant (1 mul + 1 v_exp).
// __launch_bounds__(256,2): MUST stay 2 (R2/R13: higher caps VGPR -> scratch).
__global__ __launch_bounds__(256, 2) void k_attn(unsigned short* __restrict__ Qb,
                                                 const unsigned short* __restrict__ Kb,
                                                 const unsigned short* __restrict__ Vt,
                                                 const unsigned short* __restrict__ Kbar) {
  __shared__ __align__(16) char smem[22528];
  float* pooled = (float*)(smem + 21504);   // [4 strips][16 rows][4 comps] f32
  const int tid = threadIdx.x, lane = tid & 63, wv = tid >> 6;
  const int g = lane >> 4, l15 = lane & 15;
  const int s0 = blockIdx.x * 64;
  const int h = blockIdx.y;
  const int b = blockIdx.z;
  const int bc = wv * 2 + b;
  const float scale = 0.125f;
  const float kSc2 = 0.125f * 1.44269504088896340736f;  // scale * log2(e)

  unsigned short* Qp = Qb + ((size_t)bc * Sm + s0) * Dm + h * 64;
  const unsigned short* Kp = Kb + (size_t)bc * Em * Dm + h * 64;
  const unsigned short* Vp = Vt + ((size_t)bc * Hm + h) * (64 * 192);
  char* Pw = smem + wv * 5376;              // [16 rows][336B]

  const unsigned short* kbp = Kbar + (size_t)(bc * 16 + h) * 64;
  short8 kbf[2];
  #pragma unroll
  for (int kk = 0; kk < 2; ++kk)
    kbf[kk] = *(const short8*)(kbp + kk * 32 + g * 8);

  #pragma unroll 1
  for (int st = 0; st < 4; ++st) {
    // ---- QK^T + pooled (q.kbar) ----
    short8 qf[2];
    #pragma unroll
    for (int kk = 0; kk < 2; ++kk)
      qf[kk] = *(const short8*)(Qp + (size_t)(st * 16 + l15) * Dm + kk * 32 + g * 8);
    f32x4 scb = (f32x4){0.f, 0.f, 0.f, 0.f};
    #pragma unroll
    for (int kk = 0; kk < 2; ++kk)
      scb = __builtin_amdgcn_mfma_f32_16x16x32_bf16(qf[kk], kbf[kk], scb, 0, 0, 0);
    f32x4 sc[10];
    #pragma unroll
    for (int et = 0; et < 10; ++et) {
      sc[et] = (f32x4){0.f, 0.f, 0.f, 0.f};
      #pragma unroll
      for (int kk = 0; kk < 2; ++kk) {
        short8 kf = *(const short8*)(Kp + (size_t)(et * 16 + l15) * Dm + kk * 32 + g * 8);
        sc[et] = __builtin_amdgcn_mfma_f32_16x16x32_bf16(qf[kk], kf, sc[et], 0, 0, 0);
      }
    }
    // ---- publish pooled; softmax numerators via exp2 + paired cvt_pk ----
    #pragma unroll
    for (int r = 0; r < 4; ++r)
      if (l15 == 0) pooled[(st * 16 + 4 * g + r) * 4 + wv] = scb[r] * scale;
    float rs4[4] = {0.f, 0.f, 0.f, 0.f};
    #pragma unroll
    for (int et = 0; et < 10; ++et) {
      float p0 = __builtin_exp2f(sc[et][0] * kSc2);
      float p1 = __builtin_exp2f(sc[et][1] * kSc2);
      float p2 = __builtin_exp2f(sc[et][2] * kSc2);
      float p3 = __builtin_exp2f(sc[et][3] * kSc2);
      rs4[0] += p0; rs4[1] += p1; rs4[2] += p2; rs4[3] += p3;
      __hip_bfloat162 h01 = __float22bfloat162_rn(make_float2(p0, p1));
      __hip_bfloat162 h23 = __float22bfloat162_rn(make_float2(p2, p3));
      unsigned u01, u23;
      __builtin_memcpy(&u01, &h01, 4);
      __builtin_memcpy(&u23, &h23, 4);
      char* base = Pw + (et * 16 + l15) * 2;
      *(unsigned short*)(base + (4 * g + 0) * 336) = (unsigned short)(u01 & 0xffffu);
      *(unsigned short*)(base + (4 * g + 1) * 336) = (unsigned short)(u01 >> 16);
      *(unsigned short*)(base + (4 * g + 2) * 336) = (unsigned short)(u23 & 0xffffu);
      *(unsigned short*)(base + (4 * g + 3) * 336) = (unsigned short)(u23 >> 16);
    }
    #pragma unroll
    for (int r = 0; r < 4; ++r) {
      float rs = rs4[r];
      rs += __shfl_xor(rs, 1); rs += __shfl_xor(rs, 2); rs += __shfl_xor(rs, 4); rs += __shfl_xor(rs, 8);
      rs4[r] = rs;
    }
    // ---- PV (P from per-wave LDS transpose, V^T direct from global) ----
    f32x4 oa[4];
    #pragma unroll
    for (int dt = 0; dt < 4; ++dt) oa[dt] = (f32x4){0.f, 0.f, 0.f, 0.f};
    #pragma unroll
    for (int k5 = 0; k5 < 5; ++k5) {
      short8 pf = *(const short8*)(Pw + l15 * 336 + k5 * 64 + g * 16);
      #pragma unroll
      for (int dt = 0; dt < 4; ++dt) {
        short8 vf = *(const short8*)(Vp + (size_t)(dt * 16 + l15) * 192 + k5 * 32 + g * 8);
        oa[dt] = __builtin_amdgcn_mfma_f32_16x16x32_bf16(pf, vf, oa[dt], 0, 0, 0);
      }
    }
    __syncthreads();   // all waves have written pooled[st]
    // ---- component softmax rescale + store (in-place) ----
    #pragma unroll
    for (int r = 0; r < 4; ++r) {
      float4 pl = *(const float4*)&pooled[(st * 16 + 4 * g + r) * 4];
      float m3 = fmaxf(fmaxf(pl.x, pl.y), fmaxf(pl.z, pl.w));
      float ssum = __expf(pl.x - m3) + __expf(pl.y - m3) + __expf(pl.z - m3) + __expf(pl.w - m3);
      float mine = (wv == 0) ? pl.x : (wv == 1) ? pl.y : (wv == 2) ? pl.z : pl.w;
      float srw = __expf(mine - m3) / (ssum * rs4[r]);
      #pragma unroll
      for (int dt = 0; dt < 4; ++dt)
        Qp[(size_t)(st * 16 + 4 * g + r) * Dm + dt * 16 + l15] = f2b(oa[dt][r] * srw);
    }
  }
}

extern "C" void kernel_launch(void* const* d_in, const int* in_sizes, int n_in,
                              void* d_out, int out_size, void* d_ws, size_t ws_size,
                              hipStream_t stream) {
  const float* hs  = (const float*)d_in[0];
  const float* ehs = (const float*)d_in[1];
  const float* Wq  = (const float*)d_in[2];
  const float* Wk  = (const float*)d_in[3];
  const float* Wv  = (const float*)d_in[4];
  const float* Wo  = (const float*)d_in[5];
  const float* bo  = (const float*)d_in[6];
  char* ws = (char*)d_ws;
  unsigned short* hsb  = (unsigned short*)(ws + OFF_HSB);
  unsigned short* wt   = (unsigned short*)(ws + OFF_WT);
  unsigned short* qb   = (unsigned short*)(ws + OFF_QB);
  unsigned short* kb   = (unsigned short*)(ws + OFF_KB);
  unsigned short* kbar = (unsigned short*)(ws + OFF_KBAR);
  unsigned short* vt   = (unsigned short*)(ws + OFF_VT);
  unsigned short* eb   = (unsigned short*)(ws + OFF_EHSB);

  hipLaunchKernelGGL(k_prep, dim3(7424), dim3(256), 0, stream, ehs, eb, hs, hsb, Wq, Wk, Wv, Wo, wt);
  hipLaunchKernelGGL(k_gemm_qkv, dim3(2208), dim3(256), 0, stream, hsb, eb, wt, qb, kb, vt);
  hipLaunchKernelGGL(k_kbar, dim3(128), dim3(64), 0, stream, kb, kbar);
  hipLaunchKernelGGL(k_attn, dim3(64, 16, 2), dim3(256), 0, stream, qb, kb, vt, kbar);
  hipLaunchKernelGGL(k_gemm_o, dim3(2048), dim3(256), 0, stream, qb, wt + 3 * 1048576, (float*)d_out, bo, hsb);
}

// Round 17
// 330.225 us; speedup vs baseline: 1.2886x; 1.0337x over previous
//
#include <hip/hip_runtime.h>
#include <stdint.h>

typedef __attribute__((ext_vector_type(8))) short short8;
typedef __attribute__((ext_vector_type(4))) float f32x4;
typedef __attribute__((ext_vector_type(4))) unsigned short us4;

#define DI __device__ __forceinline__

static constexpr int Dm = 1024;   // hidden dim
static constexpr int Sm = 4096;   // latent tokens
static constexpr int Em = 160;    // encoder tokens
static constexpr int Hm = 16;     // heads

// workspace layout (bytes)
static constexpr size_t OFF_HSB  = 0;           // hs bf16 [8*4096][1024] (stays live: O-proj resid)
static constexpr size_t OFF_WT   = 67108864;    // 4x Wt bf16 [1024][1024] (transposed: [N][K])
static constexpr size_t OFF_QB   = 75497472;    // Q bf16 [8*4096][1024]; attn overwrites IN-PLACE
static constexpr size_t OFF_KB   = 142606336;   // K bf16 [8*160][1024]
static constexpr size_t OFF_KBAR = 145227776;   // k-bar bf16 [8][16][64] (mean K row per bc,h)
static constexpr size_t OFF_VT   = 147849216;   // V^T bf16 [8][16][64][192]
static constexpr size_t OFF_EHSB = 150994944;   // ehs bf16 [8*160][1024]

DI unsigned short f2b(float f) {
  union { float f; unsigned u; } x; x.f = f;
  unsigned r = x.u + 0x7fffu + ((x.u >> 16) & 1u);
  return (unsigned short)(r >> 16);
}

DI float b2f(unsigned short h) {
  union { unsigned u; float f; } x; x.u = ((unsigned)h) << 16; return x.f;
}

DI void gl_lds16(const void* g, void* l) {
  __builtin_amdgcn_global_load_lds(
      (const __attribute__((address_space(1))) unsigned int*)g,
      (__attribute__((address_space(3))) unsigned int*)l, 16, 0, 0);
}

// ---------------- prep: W transpose+cvt || ehs cvt || hs cvt (one launch) ----------------
__global__ void k_prep(const float* __restrict__ ehs, unsigned short* __restrict__ eb,
                       const float* __restrict__ hs, unsigned short* __restrict__ hsb,
                       const float* __restrict__ W0, const float* __restrict__ W1,
                       const float* __restrict__ W2, const float* __restrict__ W3,
                       unsigned short* __restrict__ Wt) {
  __shared__ float t[32][33];
  const int bid = blockIdx.x, tid = threadIdx.x;
  if (bid < 4096) {
    const int bz = bid >> 10, rest = bid & 1023, by = rest >> 5, bx = rest & 31;
    const float* W = (bz == 0) ? W0 : (bz == 1) ? W1 : (bz == 2) ? W2 : W3;
    unsigned short* o = Wt + (size_t)bz * 1048576;
    const int tx = tid & 31, ty = tid >> 5;
    const int n = bx * 32 + tx, k0 = by * 32;
    #pragma unroll
    for (int j = ty; j < 32; j += 8) t[j][tx] = W[(size_t)(k0 + j) * 1024 + n];
    __syncthreads();
    #pragma unroll
    for (int j = ty; j < 32; j += 8)
      o[(size_t)(bx * 32 + j) * 1024 + k0 + tx] = f2b(t[tx][j]);
  } else if (bid < 5376) {
    const int i = (bid - 4096) * 256 + tid;
    float4 v = ((const float4*)ehs)[i];
    us4 o = { f2b(v.x), f2b(v.y), f2b(v.z), f2b(v.w) };
    *(us4*)(eb + (size_t)i * 4) = o;
  } else {
    for (int i = (bid - 5376) * 256 + tid; i < 8388608; i += 2048 * 256) {
      float4 v = ((const float4*)hs)[i];
      us4 o = { f2b(v.x), f2b(v.y), f2b(v.z), f2b(v.w) };
      *(us4*)(hsb + (size_t)i * 4) = o;
    }
  }
}

// ---------------- fused Q + K + V projection GEMM (one launch) ----------------
__global__ __launch_bounds__(256, 4) void k_gemm_qkv(const unsigned short* __restrict__ hsb,
                                                     const unsigned short* __restrict__ eb,
                                                     const unsigned short* __restrict__ Wt,
                                                     unsigned short* __restrict__ qb,
                                                     unsigned short* __restrict__ kb,
                                                     unsigned short* __restrict__ vt) {
  __shared__ __align__(16) char smem[32768];
  char* As = smem;
  char* Bs = smem + 16384;
  const int bid = blockIdx.x, tid = threadIdx.x;
  const int lane = tid & 63;
  const int l15 = lane & 15;
  const int g = lane >> 4;
  const int wv = tid >> 6;
  const int wr = wv >> 1, wc = wv & 1;

  const bool isKV = (bid < 160);
  int m0, n0;
  const unsigned short *Ap, *Bt;
  if (isKV) {
    const int z = bid / 80, rr = bid - z * 80;
    m0 = (rr % 10) * 128; n0 = (rr / 10) * 128;
    Ap = eb; Bt = Wt + (size_t)(1 + z) * 1048576;
  } else {
    const int q = bid - 160;
    m0 = ((q >> 6) * 8 + (q & 7)) * 128;
    n0 = ((q >> 3) & 7) * 128;
    Ap = hsb; Bt = Wt;
  }

  f32x4 acc[4][4];
  #pragma unroll
  for (int i = 0; i < 4; ++i)
    #pragma unroll
    for (int j = 0; j < 4; ++j) acc[i][j] = (f32x4){0.f, 0.f, 0.f, 0.f};

  for (int t = 0; t < 16; ++t) {
    __syncthreads();
    #pragma unroll
    for (int is = 0; is < 4; ++is) {
      int ch = is * 256 + tid;
      int row = ch >> 3, j = ch & 7;
      int sj = (j ^ (row & 7)) * 8;
      gl_lds16(Ap + (size_t)(m0 + row) * 1024 + t * 64 + sj, As + ch * 16);
      gl_lds16(Bt + (size_t)(n0 + row) * 1024 + t * 64 + sj, Bs + ch * 16);
    }
    __syncthreads();
    short8 af[2][4], bf[2][4];
    #pragma unroll
    for (int kk = 0; kk < 2; ++kk)
      #pragma unroll
      for (int mt = 0; mt < 4; ++mt) {
        af[kk][mt] = *(const short8*)(As + (wr * 64 + mt * 16 + l15) * 128 + ((kk * 64 + g * 16) ^ ((l15 & 7) << 4)));
        bf[kk][mt] = *(const short8*)(Bs + (wc * 64 + mt * 16 + l15) * 128 + ((kk * 64 + g * 16) ^ ((l15 & 7) << 4)));
      }
    #pragma unroll
    for (int kk = 0; kk < 2; ++kk)
      #pragma unroll
      for (int mt = 0; mt < 4; ++mt)
        #pragma unroll
        for (int nt = 0; nt < 4; ++nt)
          acc[mt][nt] = __builtin_amdgcn_mfma_f32_16x16x32_bf16(af[kk][mt], bf[kk][nt], acc[mt][nt], 0, 0, 0);
  }

  if (isKV) {
    const int z = bid / 80;
    #pragma unroll
    for (int mt = 0; mt < 4; ++mt)
      #pragma unroll
      for (int nt = 0; nt < 4; ++nt)
        #pragma unroll
        for (int r = 0; r < 4; ++r) {
          int row = m0 + wr * 64 + mt * 16 + 4 * g + r;   // [0,1280)
          int col = n0 + wc * 64 + nt * 16 + l15;         // [0,1024)
          unsigned short hv = f2b(acc[mt][nt][r]);
          if (z == 0) {
            kb[(size_t)row * 1024 + col] = hv;
          } else {
            int bc = row / 160, e = row - bc * 160;       // h = col>>6, d = col&63
            vt[((size_t)(bc * 16 + (col >> 6)) * 64 + (col & 63)) * 192 + e] = hv;
          }
        }
  } else {
    __syncthreads();
    unsigned short* Cl = (unsigned short*)smem;
    #pragma unroll
    for (int mt = 0; mt < 4; ++mt)
      #pragma unroll
      for (int nt = 0; nt < 4; ++nt)
        #pragma unroll
        for (int r = 0; r < 4; ++r)
          Cl[(wr * 64 + mt * 16 + 4 * g + r) * 128 + wc * 64 + nt * 16 + l15] = f2b(acc[mt][nt][r]);
    __syncthreads();
    #pragma unroll
    for (int j = 0; j < 8; ++j) {
      int ch = j * 256 + tid;
      int row = ch >> 4, sl = ch & 15;
      __builtin_nontemporal_store(*(const short8*)(Cl + row * 128 + sl * 8),
          (short8*)(qb + (size_t)(m0 + row) * 1024 + n0 + sl * 8));
    }
  }
}

// ---------------- k-bar: mean K row per (bc,h) ----------------
__global__ void k_kbar(const unsigned short* __restrict__ kb, unsigned short* __restrict__ kbar) {
  const int bh = blockIdx.x, d = threadIdx.x;
  const int bc = bh >> 4, h = bh & 15;
  const unsigned short* src = kb + ((size_t)bc * Em) * Dm + h * 64 + d;
  float s = 0.f;
  #pragma unroll 4
  for (int e = 0; e < Em; ++e) s += b2f(src[(size_t)e * Dm]);
  kbar[(size_t)bh * 64 + d] = f2b(s * (1.f / 160.f));
}

// ---------------- O-projection GEMM: fp32 out + bias + bf16 residual ----------------
__global__ __launch_bounds__(256, 4) void k_gemm_o(const unsigned short* __restrict__ A,
                                                   const unsigned short* __restrict__ Bt,
                                                   float* __restrict__ Cout,
                                                   const float* __restrict__ bias,
                                                   const unsigned short* __restrict__ residb) {
  __shared__ __align__(16) char smem[32768];
  char* As = smem;
  char* Bs = smem + 16384;
  const int tid = threadIdx.x;
  const int lane = tid & 63;
  const int l15 = lane & 15;
  const int g = lane >> 4;
  const int wv = tid >> 6;
  const int wr = wv >> 1, wc = wv & 1;
  const int bid = blockIdx.x;
  const int m0 = ((bid >> 6) * 8 + (bid & 7)) * 128;
  const int n0 = ((bid >> 3) & 7) * 128;

  f32x4 acc[4][4];
  #pragma unroll
  for (int i = 0; i < 4; ++i)
    #pragma unroll
    for (int j = 0; j < 4; ++j) acc[i][j] = (f32x4){0.f, 0.f, 0.f, 0.f};

  for (int t = 0; t < 16; ++t) {
    __syncthreads();
    #pragma unroll
    for (int is = 0; is < 4; ++is) {
      int ch = is * 256 + tid;
      int row = ch >> 3, j = ch & 7;
      int sj = (j ^ (row & 7)) * 8;
      gl_lds16(A  + (size_t)(m0 + row) * 1024 + t * 64 + sj, As + ch * 16);
      gl_lds16(Bt + (size_t)(n0 + row) * 1024 + t * 64 + sj, Bs + ch * 16);
    }
    __syncthreads();
    short8 af[2][4], bf[2][4];
    #pragma unroll
    for (int kk = 0; kk < 2; ++kk)
      #pragma unroll
      for (int mt = 0; mt < 4; ++mt) {
        af[kk][mt] = *(const short8*)(As + (wr * 64 + mt * 16 + l15) * 128 + ((kk * 64 + g * 16) ^ ((l15 & 7) << 4)));
        bf[kk][mt] = *(const short8*)(Bs + (wc * 64 + mt * 16 + l15) * 128 + ((kk * 64 + g * 16) ^ ((l15 & 7) << 4)));
      }
    #pragma unroll
    for (int kk = 0; kk < 2; ++kk)
      #pragma unroll
      for (int mt = 0; mt < 4; ++mt)
        #pragma unroll
        for (int nt = 0; nt < 4; ++nt)
          acc[mt][nt] = __builtin_amdgcn_mfma_f32_16x16x32_bf16(af[kk][mt], bf[kk][nt], acc[mt][nt], 0, 0, 0);
  }

  #pragma unroll
  for (int mt = 0; mt < 4; ++mt)
    #pragma unroll
    for (int nt = 0; nt < 4; ++nt)
      #pragma unroll
      for (int r = 0; r < 4; ++r) {
        size_t row = (size_t)(m0 + wr * 64 + mt * 16 + 4 * g + r);
        int col = n0 + wc * 64 + nt * 16 + l15;
        size_t idx = row * 1024 + col;
        unsigned short rh = __builtin_nontemporal_load(residb + idx);
        Cout[idx] = acc[mt][nt][r] + bias[col] + b2f(rh);
      }
}

// ---------------- fused decomposing attention v7 (v4 body, et-loop split 2x5) ----------------
// Identical algorithm/barriers to R14 v4 (known 105us). Only change: QK^T + softmax
// processed in TWO halves of 5 et-tiles -> peak live sc[] drops 40->20 VGPRs,
// cutting per-wave registers (~185 -> ~165) so HW fits 3 waves/SIMD instead of 2.
// rs accumulation order unchanged (et 0..9) -> bit-identical results.
// __launch_bounds__(256,2): MUST stay 2 (R2/R13: forced cap -> scratch spill).
__global__ __launch_bounds__(256, 2) void k_attn(unsigned short* __restrict__ Qb,
                                                 const unsigned short* __restrict__ Kb,
                                                 const unsigned short* __restrict__ Vt,
                                                 const unsigned short* __restrict__ Kbar) {
  __shared__ __align__(16) char smem[22528];
  float* pooled = (float*)(smem + 21504);   // [4 strips][16 rows][4 comps] f32
  const int tid = threadIdx.x, lane = tid & 63, wv = tid >> 6;
  const int g = lane >> 4, l15 = lane & 15;
  const int s0 = blockIdx.x * 64;
  const int h = blockIdx.y;
  const int b = blockIdx.z;
  const int bc = wv * 2 + b;
  const float scale = 0.125f;

  unsigned short* Qp = Qb + ((size_t)bc * Sm + s0) * Dm + h * 64;
  const unsigned short* Kp = Kb + (size_t)bc * Em * Dm + h * 64;
  const unsigned short* Vp = Vt + ((size_t)bc * Hm + h) * (64 * 192);
  char* Pw = smem + wv * 5376;              // [16 rows][336B]

  const unsigned short* kbp = Kbar + (size_t)(bc * 16 + h) * 64;
  short8 kbf[2];
  #pragma unroll
  for (int kk = 0; kk < 2; ++kk)
    kbf[kk] = *(const short8*)(kbp + kk * 32 + g * 8);

  #pragma unroll 1
  for (int st = 0; st < 4; ++st) {
    // ---- Q fragments + pooled (q.kbar) ----
    short8 qf[2];
    #pragma unroll
    for (int kk = 0; kk < 2; ++kk)
      qf[kk] = *(const short8*)(Qp + (size_t)(st * 16 + l15) * Dm + kk * 32 + g * 8);
    f32x4 scb = (f32x4){0.f, 0.f, 0.f, 0.f};
    #pragma unroll
    for (int kk = 0; kk < 2; ++kk)
      scb = __builtin_amdgcn_mfma_f32_16x16x32_bf16(qf[kk], kbf[kk], scb, 0, 0, 0);
    #pragma unroll
    for (int r = 0; r < 4; ++r)
      if (l15 == 0) pooled[(st * 16 + 4 * g + r) * 4 + wv] = scb[r] * scale;

    // ---- QK^T + softmax numerators in two halves of 5 et-tiles ----
    float rsp[4] = {0.f, 0.f, 0.f, 0.f};
    #pragma unroll
    for (int hf = 0; hf < 2; ++hf) {
      f32x4 sch[5];
      #pragma unroll
      for (int e5 = 0; e5 < 5; ++e5) {
        const int et = hf * 5 + e5;
        sch[e5] = (f32x4){0.f, 0.f, 0.f, 0.f};
        #pragma unroll
        for (int kk = 0; kk < 2; ++kk) {
          short8 kf = *(const short8*)(Kp + (size_t)(et * 16 + l15) * Dm + kk * 32 + g * 8);
          sch[e5] = __builtin_amdgcn_mfma_f32_16x16x32_bf16(qf[kk], kf, sch[e5], 0, 0, 0);
        }
      }
      #pragma unroll
      for (int r = 0; r < 4; ++r) {
        float rs = rsp[r];
        #pragma unroll
        for (int e5 = 0; e5 < 5; ++e5) {
          const int et = hf * 5 + e5;
          float p = __expf(sch[e5][r] * scale);
          rs += p;
          *(unsigned short*)(Pw + (4 * g + r) * 336 + (et * 16 + l15) * 2) = f2b(p);
        }
        rsp[r] = rs;
      }
    }
    float rs4[4];
    #pragma unroll
    for (int r = 0; r < 4; ++r) {
      float rs = rsp[r];
      rs += __shfl_xor(rs, 1); rs += __shfl_xor(rs, 2); rs += __shfl_xor(rs, 4); rs += __shfl_xor(rs, 8);
      rs4[r] = rs;
    }
    // ---- PV (P from per-wave LDS transpose, V^T direct from global) ----
    f32x4 oa[4];
    #pragma unroll
    for (int dt = 0; dt < 4; ++dt) oa[dt] = (f32x4){0.f, 0.f, 0.f, 0.f};
    #pragma unroll
    for (int k5 = 0; k5 < 5; ++k5) {
      short8 pf = *(const short8*)(Pw + l15 * 336 + k5 * 64 + g * 16);
      #pragma unroll
      for (int dt = 0; dt < 4; ++dt) {
        short8 vf = *(const short8*)(Vp + (size_t)(dt * 16 + l15) * 192 + k5 * 32 + g * 8);
        oa[dt] = __builtin_amdgcn_mfma_f32_16x16x32_bf16(pf, vf, oa[dt], 0, 0, 0);
      }
    }
    __syncthreads();   // all waves have written pooled[st]
    // ---- component softmax rescale + store (in-place) ----
    #pragma unroll
    for (int r = 0; r < 4; ++r) {
      float4 pl = *(const float4*)&pooled[(st * 16 + 4 * g + r) * 4];
      float m3 = fmaxf(fmaxf(pl.x, pl.y), fmaxf(pl.z, pl.w));
      float ssum = __expf(pl.x - m3) + __expf(pl.y - m3) + __expf(pl.z - m3) + __expf(pl.w - m3);
      float mine = (wv == 0) ? pl.x : (wv == 1) ? pl.y : (wv == 2) ? pl.z : pl.w;
      float srw = __expf(mine - m3) / (ssum * rs4[r]);
      #pragma unroll
      for (int dt = 0; dt < 4; ++dt)
        Qp[(size_t)(st * 16 + 4 * g + r) * Dm + dt * 16 + l15] = f2b(oa[dt][r] * srw);
    }
  }
}

extern "C" void kernel_launch(void* const* d_in, const int* in_sizes, int n_in,
                              void* d_out, int out_size, void* d_ws, size_t ws_size,
                              hipStream_t stream) {
  const float* hs  = (const float*)d_in[0];
  const float* ehs = (const float*)d_in[1];
  const float* Wq  = (const float*)d_in[2];
  const float* Wk  = (const float*)d_in[3];
  const float* Wv  = (const float*)d_in[4];
  const float* Wo  = (const float*)d_in[5];
  const float* bo  = (const float*)d_in[6];
  char* ws = (char*)d_ws;
  unsigned short* hsb  = (unsigned short*)(ws + OFF_HSB);
  unsigned short* wt   = (unsigned short*)(ws + OFF_WT);
  unsigned short* qb   = (unsigned short*)(ws + OFF_QB);
  unsigned short* kb   = (unsigned short*)(ws + OFF_KB);
  unsigned short* kbar = (unsigned short*)(ws + OFF_KBAR);
  unsigned short* vt   = (unsigned short*)(ws + OFF_VT);
  unsigned short* eb   = (unsigned short*)(ws + OFF_EHSB);

  hipLaunchKernelGGL(k_prep, dim3(7424), dim3(256), 0, stream, ehs, eb, hs, hsb, Wq, Wk, Wv, Wo, wt);
  hipLaunchKernelGGL(k_gemm_qkv, dim3(2208), dim3(256), 0, stream, hsb, eb, wt, qb, kb, vt);
  hipLaunchKernelGGL(k_kbar, dim3(128), dim3(64), 0, stream, kb, kbar);
  hipLaunchKernelGGL(k_attn, dim3(64, 16, 2), dim3(256), 0, stream, qb, kb, vt, kbar);
  hipLaunchKernelGGL(k_gemm_o, dim3(2048), dim3(256), 0, stream, qb, wt + 3 * 1048576, (float*)d_out, bo, hsb);
}